// Round 13
// baseline (1056.393 us; speedup 1.0000x reference)
//
#include <hip/hip_runtime.h>
#include <hip/hip_bf16.h>

typedef unsigned short u16;
typedef unsigned char u8;

// Problem constants: B_=2, T=4096, DIM=1024, HEADS=16, DH=64, NH(rounds)=8,
// NB(buckets)=64, BUCKET=64, merged batch-heads M=32, chunks/merged-head=512.
//
// ROUND 23 (session r12): attn_chunk had 7.86e7 bank-conflict cycles (~128us:
// V-transpose scalar-short writes, 8-way) + redundant hi/lo conversion (each
// token split 16x across rounds; VALUBusy 44%). Hoist: qk_prep converts
// g_qk32 -> g_qkh/g_qkl + g_rn ONCE; v_gemm writes hi/lo directly (g_v32
// deleted); attn_chunk stages by pure copies, V transposed via paired-key
// dword writes (64 lanes @ 4B stride = 2-way, free). All arithmetic inputs
// bit-identical to r11 -> absmax must stay exactly 4.882812e-4.
// BIT-EXACTNESS INVARIANTS (calibrated to host OpenBLAS, r1 PASS):
//  - qk GEMM: fp32 FMA chain ascending k, panel folds {384,704}, panel sums
//    combined by plain adds in panel order (RMW flush). DO NOT TOUCH.
//  - hash: ascending-f FMA chain, argmax first-occurrence strict >/<.

__device__ __forceinline__ bool qk_fold_point(int k0) {
    return k0 == 384 || k0 == 704;
}

typedef __attribute__((ext_vector_type(8))) short bf16x8;
typedef __attribute__((ext_vector_type(4))) short bf16x4s;
typedef __attribute__((ext_vector_type(4))) float f32x4;

#define MFMA_BF16(A, B, C) __builtin_amdgcn_mfma_f32_16x16x32_bf16(A, B, C, 0, 0, 0)

__device__ __forceinline__ unsigned short f2bf(float x) {
    unsigned u = __float_as_uint(x);
    u += 0x7FFFu + ((u >> 16) & 1u);
    return (unsigned short)(u >> 16);
}
__device__ __forceinline__ float bf2f(unsigned short hv) {
    return __uint_as_float(((unsigned)hv) << 16);
}

// ---- scratch in static device globals ----
__device__ static float g_qk32[32u * 4096u * 64u];   // 32 MB [m][t][d] fp32 (hash)
__device__ static u16   g_qkh [32u * 4096u * 64u];   // 16 MB bf16 hi
__device__ static u16   g_qkl [32u * 4096u * 64u];   // 16 MB bf16 lo
__device__ static u16   g_vh  [32u * 4096u * 64u];   // 16 MB
__device__ static u16   g_vl  [32u * 4096u * 64u];   // 16 MB
__device__ static float g_rn  [32u * 4096u];         // 512 KB per-token 1/||k||
__device__ static float g_ctx [2u * 4096u * 1024u];  // 32 MB [b][t][head*64+d]
__device__ static float g_bo  [32u * 8u * 4096u * 64u]; // 256 MB [m][h][t][d]
__device__ static float g_logits[32u * 8u * 4096u];  //  4 MB [m][h][t]
__device__ static u16   g_st  [32u * 8u * 4096u];    //  2 MB sorted token idx
__device__ static u8    g_bkt [32u * 8u * 4096u];    //  1 MB bucket ids

// ---------------------------------------------------------------------------
// Kernel 1a: qk GEMM. 128x128 C tile, 8x8 per thread, K-step 32, RMW
// fold-flush. grid (64, 8). Bit-pinned fp32 chain (r8 version, replay-proven).
// ---------------------------------------------------------------------------
__global__ __launch_bounds__(256) void qk_gemm(
    const float* __restrict__ x, const float* __restrict__ w_qk)
{
    __shared__ __align__(16) float As[32 * 132];  // [kk][row]
    __shared__ __align__(16) float Ws[32 * 192];  // [kk][(c>>3)*12 + (c&7)]
    const int tid = threadIdx.x;
    const int bm = blockIdx.x;
    const int hp = blockIdx.y;          // head pair 0..7
    const int ncol0 = hp * 128;
    const int row0 = bm * 128;
    const int tx = tid & 15, ty = tid >> 4;
    const int lr = tid >> 1;
    const int lk = (tid & 1) * 16;
    float acc[8][8] = {};

    const int b_ = row0 >> 12;
    const int head = hp * 2 + (tx >> 3);
    const int m = b_ * 16 + head;
    const int d0 = (tx * 8) & 63;
    float* __restrict__ dst = g_qk32;
    int first_panel = 1;

    for (int k0 = 0; k0 < 1024; k0 += 32) {
        if (qk_fold_point(k0)) {
#pragma unroll
            for (int i = 0; i < 8; i++) {
                const int t = (row0 & 4095) + ty * 8 + i;
                float* __restrict__ cp =
                    &dst[(((size_t)m * 4096 + t) << 6) + d0];
                float4 s0, s1;
                s0.x = acc[i][0]; s0.y = acc[i][1];
                s0.z = acc[i][2]; s0.w = acc[i][3];
                s1.x = acc[i][4]; s1.y = acc[i][5];
                s1.z = acc[i][6]; s1.w = acc[i][7];
                if (!first_panel) {
                    const float4 c0 = *(const float4*)&cp[0];
                    const float4 c1 = *(const float4*)&cp[4];
                    s0.x += c0.x; s0.y += c0.y; s0.z += c0.z; s0.w += c0.w;
                    s1.x += c1.x; s1.y += c1.y; s1.z += c1.z; s1.w += c1.w;
                }
                *(float4*)&cp[0] = s0;
                *(float4*)&cp[4] = s1;
#pragma unroll
                for (int j = 0; j < 8; j++) acc[i][j] = 0.f;
            }
            first_panel = 0;
        }
        float av[16], wv[16];
#pragma unroll
        for (int q4 = 0; q4 < 4; q4++) {
            *(float4*)&av[q4 * 4] =
                *(const float4*)(x + (size_t)(row0 + lr) * 1024 + k0 + lk + q4 * 4);
            *(float4*)&wv[q4 * 4] =
                *(const float4*)(w_qk + (size_t)(ncol0 + lr) * 1024 + k0 + lk + q4 * 4);
        }
        __syncthreads();
#pragma unroll
        for (int q = 0; q < 16; q++) {
            As[(lk + q) * 132 + lr] = av[q];
            Ws[(lk + q) * 192 + (lr >> 3) * 12 + (lr & 7)] = wv[q];
        }
        __syncthreads();
#pragma unroll 4
        for (int kk = 0; kk < 32; kk++) {
            const float4 a0 = *(const float4*)&As[kk * 132 + ty * 8];
            const float4 a1 = *(const float4*)&As[kk * 132 + ty * 8 + 4];
            const float4 b0 = *(const float4*)&Ws[kk * 192 + tx * 12];
            const float4 b1 = *(const float4*)&Ws[kk * 192 + tx * 12 + 4];
            const float aa[8] = {a0.x, a0.y, a0.z, a0.w, a1.x, a1.y, a1.z, a1.w};
            const float bb[8] = {b0.x, b0.y, b0.z, b0.w, b1.x, b1.y, b1.z, b1.w};
#pragma unroll
            for (int i = 0; i < 8; i++)
#pragma unroll
                for (int j = 0; j < 8; j++)
                    acc[i][j] = fmaf(aa[i], bb[j], acc[i][j]);
        }
    }
#pragma unroll
    for (int i = 0; i < 8; i++) {
        const int t = (row0 & 4095) + ty * 8 + i;
        float* __restrict__ cp = &dst[(((size_t)m * 4096 + t) << 6) + d0];
        const float4 c0 = *(const float4*)&cp[0];
        const float4 c1 = *(const float4*)&cp[4];
        float4 s0, s1;
        s0.x = acc[i][0] + c0.x; s0.y = acc[i][1] + c0.y;
        s0.z = acc[i][2] + c0.z; s0.w = acc[i][3] + c0.w;
        s1.x = acc[i][4] + c1.x; s1.y = acc[i][5] + c1.y;
        s1.z = acc[i][6] + c1.z; s1.w = acc[i][7] + c1.w;
        *(float4*)&cp[0] = s0;
        *(float4*)&cp[4] = s1;
    }
}

// ---------------------------------------------------------------------------
// Kernel 1a'': qk_prep — one thread per (m,t): hi/lo split of g_qk32 +
// per-token 1/||k|| (same ascending-f fp32 chain as r11's in-kernel rnorm).
// grid 512, block 256.
// ---------------------------------------------------------------------------
__global__ __launch_bounds__(256) void qk_prep()
{
    const int row = blockIdx.x * 256 + threadIdx.x;   // m*4096 + t
    const float* __restrict__ qp = g_qk32 + ((size_t)row << 6);
    u16* __restrict__ qh = g_qkh + ((size_t)row << 6);
    u16* __restrict__ ql = g_qkl + ((size_t)row << 6);
    float ss = 0.f;
#pragma unroll
    for (int f4 = 0; f4 < 16; f4++) {
        const float4 v = *(const float4*)&qp[f4 * 4];
        const float vv[4] = {v.x, v.y, v.z, v.w};
        bf16x4s hi4, lo4;
#pragma unroll
        for (int e = 0; e < 4; e++) {
            const unsigned short hv = f2bf(vv[e]);
            const unsigned short lv = f2bf(vv[e] - bf2f(hv));
            hi4[e] = (short)hv;
            lo4[e] = (short)lv;
            const float recon = bf2f(hv) + bf2f(lv);
            ss += recon * recon;
        }
        *(bf16x4s*)&qh[f4 * 4] = hi4;
        *(bf16x4s*)&ql[f4 * 4] = lo4;
    }
    g_rn[row] = 1.0f / fmaxf(sqrtf(ss), 1e-12f);
}

// ---------------------------------------------------------------------------
// Kernel 1a': V GEMM via bf16 hi/lo 3-term MFMA (continuous path).
// 128x128 tile, 4 waves, wave = 64x64. grid (64, 8).
// Epilogue writes hi/lo bf16 directly (g_v32 eliminated).
// ---------------------------------------------------------------------------
__global__ __launch_bounds__(256) void v_gemm(
    const float* __restrict__ x, const float* __restrict__ w_v)
{
    __shared__ __align__(16) short Ah[128 * 40], Al[128 * 40];
    __shared__ __align__(16) short Bh[128 * 40], Bl[128 * 40];
    const int tid = threadIdx.x;
    const int row0 = blockIdx.x * 128;
    const int col0 = blockIdx.y * 128;
    const int w = tid >> 6, lane = tid & 63;
    const int llo = lane & 15, lhi = lane >> 4;
    const int wr0 = (w >> 1) * 64, wc0 = (w & 1) * 64;
    const int lr = tid >> 1;            // stage row 0..127
    const int lh = (tid & 1) * 16;      // stage k-offset {0,16}
    f32x4 Acc[4][4];
#pragma unroll
    for (int rt = 0; rt < 4; rt++)
#pragma unroll
        for (int ct = 0; ct < 4; ct++) Acc[rt][ct] = f32x4{0.f, 0.f, 0.f, 0.f};

    for (int k0 = 0; k0 < 1024; k0 += 32) {
        float av[16], bv[16];
#pragma unroll
        for (int q4 = 0; q4 < 4; q4++) {
            *(float4*)&av[q4 * 4] =
                *(const float4*)(x + (size_t)(row0 + lr) * 1024 + k0 + lh + q4 * 4);
            *(float4*)&bv[q4 * 4] =
                *(const float4*)(w_v + (size_t)(col0 + lr) * 1024 + k0 + lh + q4 * 4);
        }
        __syncthreads();
        short ah[16], al2[16], bh2[16], bl2[16];
#pragma unroll
        for (int e = 0; e < 16; e++) {
            unsigned short hv = f2bf(av[e]);
            ah[e] = (short)hv;
            al2[e] = (short)f2bf(av[e] - bf2f(hv));
            hv = f2bf(bv[e]);
            bh2[e] = (short)hv;
            bl2[e] = (short)f2bf(bv[e] - bf2f(hv));
        }
        *(bf16x8*)&Ah[lr * 40 + lh] = *(bf16x8*)&ah[0];
        *(bf16x8*)&Ah[lr * 40 + lh + 8] = *(bf16x8*)&ah[8];
        *(bf16x8*)&Al[lr * 40 + lh] = *(bf16x8*)&al2[0];
        *(bf16x8*)&Al[lr * 40 + lh + 8] = *(bf16x8*)&al2[8];
        *(bf16x8*)&Bh[lr * 40 + lh] = *(bf16x8*)&bh2[0];
        *(bf16x8*)&Bh[lr * 40 + lh + 8] = *(bf16x8*)&bh2[8];
        *(bf16x8*)&Bl[lr * 40 + lh] = *(bf16x8*)&bl2[0];
        *(bf16x8*)&Bl[lr * 40 + lh + 8] = *(bf16x8*)&bl2[8];
        __syncthreads();
        bf16x8 Afh[4], Afl[4];
#pragma unroll
        for (int rt = 0; rt < 4; rt++) {
            const int off = (wr0 + rt * 16 + llo) * 40 + lhi * 8;
            Afh[rt] = *(const bf16x8*)&Ah[off];
            Afl[rt] = *(const bf16x8*)&Al[off];
        }
#pragma unroll
        for (int ct = 0; ct < 4; ct++) {
            const int off = (wc0 + ct * 16 + llo) * 40 + lhi * 8;
            const bf16x8 Bfh = *(const bf16x8*)&Bh[off];
            const bf16x8 Bfl = *(const bf16x8*)&Bl[off];
#pragma unroll
            for (int rt = 0; rt < 4; rt++) {
                Acc[rt][ct] = MFMA_BF16(Afh[rt], Bfh, Acc[rt][ct]);
                Acc[rt][ct] = MFMA_BF16(Afh[rt], Bfl, Acc[rt][ct]);
                Acc[rt][ct] = MFMA_BF16(Afl[rt], Bfh, Acc[rt][ct]);
            }
        }
    }
    // epilogue: hi/lo split directly into g_vh/g_vl [m][t][d]
#pragma unroll
    for (int rt = 0; rt < 4; rt++) {
#pragma unroll
        for (int ct = 0; ct < 4; ct++) {
            const int col = col0 + wc0 + ct * 16 + llo;
            const int hd = col >> 6, d = col & 63;
#pragma unroll
            for (int r = 0; r < 4; r++) {
                const int row = row0 + wr0 + rt * 16 + lhi * 4 + r;
                const int m = ((row >> 12) << 4) + hd;
                const int t = row & 4095;
                const float val = Acc[rt][ct][r];
                const unsigned short hv = f2bf(val);
                const size_t o = (((size_t)m * 4096 + t) << 6) + d;
                g_vh[o] = hv;
                g_vl[o] = f2bf(val - bf2f(hv));
            }
        }
    }
}

// ---------------------------------------------------------------------------
// Kernel 1b: LSH hash (unchanged, bit-pinned).
// ---------------------------------------------------------------------------
__global__ __launch_bounds__(256) void hash_kernel(
    const float* __restrict__ rot_in)
{
    __shared__ __align__(16) float rotS[16384];  // [f][h][i]
    const int tid = threadIdx.x;
    for (int idx = tid; idx < 16384; idx += 256)
        rotS[idx] = rot_in[idx];
    __syncthreads();
    const int row = blockIdx.x * 256 + tid;      // m*4096 + t
    const int m = row >> 12, t = row & 4095;
    float q[64];
    const float* __restrict__ qp = g_qk32 + ((size_t)row << 6);
#pragma unroll
    for (int f4 = 0; f4 < 16; f4++)
        *(float4*)&q[f4 * 4] = *(const float4*)&qp[f4 * 4];
#pragma unroll 1
    for (int hh = 0; hh < 8; hh++) {
        float bp = -3.4e38f; int ip = 0;
        float mn = 3.4e38f;  int im = 0;
#pragma unroll 1
        for (int ib = 0; ib < 8; ib++) {
            float s0 = 0.f, s1 = 0.f, s2 = 0.f, s3 = 0.f;
#pragma unroll
            for (int f = 0; f < 64; f++) {
                const float4 r4 =
                    *(const float4*)&rotS[f * 256 + hh * 32 + ib * 4];
                const float qf = q[f];
                s0 = fmaf(qf, r4.x, s0);
                s1 = fmaf(qf, r4.y, s1);
                s2 = fmaf(qf, r4.z, s2);
                s3 = fmaf(qf, r4.w, s3);
            }
            const int i0 = ib * 4;
            if (s0 > bp) { bp = s0; ip = i0; }
            if (s0 < mn) { mn = s0; im = i0; }
            if (s1 > bp) { bp = s1; ip = i0 + 1; }
            if (s1 < mn) { mn = s1; im = i0 + 1; }
            if (s2 > bp) { bp = s2; ip = i0 + 2; }
            if (s2 < mn) { mn = s2; im = i0 + 2; }
            if (s3 > bp) { bp = s3; ip = i0 + 3; }
            if (s3 < mn) { mn = s3; im = i0 + 3; }
        }
        const int bi = (-mn > bp) ? (32 + im) : ip;
        g_bkt[((size_t)m * 8 + hh) * 4096 + t] = (u8)bi;
    }
}

// ---------------------------------------------------------------------------
// Kernel 2: per-(m,h) stable counting sort (unchanged).
// ---------------------------------------------------------------------------
__global__ __launch_bounds__(256) void sort_kernel()
{
    __shared__ u16 hist[256 * 64];   // [chunk][bucket]
    __shared__ u8 bkt[4096];
    __shared__ int rowsum[64];
    __shared__ int rowbase[64];
    const int tid = threadIdx.x;
    const int mh = blockIdx.x;
    const u8* __restrict__ src = g_bkt + (size_t)mh * 4096;
    for (int i = tid; i < 4096; i += 256) bkt[i] = src[i];
    for (int i = tid; i < 16384; i += 256) hist[i] = 0;
    __syncthreads();
#pragma unroll
    for (int k = 0; k < 16; k++) {
        const int t = tid * 16 + k;
        hist[tid * 64 + (bkt[t] & 63)]++;  // own row -> race-free, stable
    }
    __syncthreads();
    if (tid < 64) {
        int s = 0;
        for (int c = 0; c < 256; c++) s += hist[c * 64 + tid];
        rowsum[tid] = s;
    }
    __syncthreads();
    if (tid == 0) {
        int acc = 0;
        for (int b = 0; b < 64; b++) { rowbase[b] = acc; acc += rowsum[b]; }
    }
    __syncthreads();
    if (tid < 64) {
        int run = rowbase[tid];
        for (int c = 0; c < 256; c++) {
            const int tmp = hist[c * 64 + tid];
            hist[c * 64 + tid] = (u16)run;
            run += tmp;
        }
    }
    __syncthreads();
    u16* __restrict__ dst = g_st + (size_t)mh * 4096;
#pragma unroll
    for (int k = 0; k < 16; k++) {
        const int t = tid * 16 + k;
        const int b = bkt[t] & 63;
        const int pos = hist[tid * 64 + b]++;
        dst[pos & 4095] = (u16)t;
    }
}

// ---------------------------------------------------------------------------
// Kernel 3: fused per-chunk attention, MFMA bf16-split. Staging is now pure
// copies from precomputed hi/lo buffers; V transposed via paired-key dword
// writes (conflict-free); rnorm loaded from g_rn.
// ---------------------------------------------------------------------------
__global__ __launch_bounds__(256) void attn_chunk()
{
    __shared__ __align__(16) short ksb[128 * 72];
    __shared__ __align__(16) short ksl[128 * 72];
    __shared__ __align__(16) short vth[64 * 136];
    __shared__ __align__(16) short vtl[64 * 136];
    __shared__ float rnorm[128];
    __shared__ int tk[128];
    const int tid = threadIdx.x;
    const int bid = blockIdx.x;
    const int m = bid >> 9, c = bid & 511;
    const int h = c >> 6, cc = c & 63;
    const int cp = (c + 511) & 511;            // look-one-back, wraps all 512
    const int hpp = cp >> 6, ccp = cp & 63;
    const u16* __restrict__ stm = g_st + (size_t)m * 8 * 4096;
    if (tid < 128) {
        const int hh = (tid < 64) ? h : hpp;
        const int cq = (tid < 64) ? cc : ccp;
        tk[tid] = (int)stm[hh * 4096 + cq * 64 + (tid & 63)] & 4095;
    }
    __syncthreads();
    const size_t mbase = (size_t)m << 18;      // m*4096*64
    // --- K copy: hi/lo rows, b128 chunks ---
    for (int idx = tid; idx < 128 * 8; idx += 256) {
        const int j = idx >> 3, s8 = (idx & 7) * 8;
        const size_t so = mbase + ((size_t)tk[j] << 6) + s8;
        *(bf16x8*)&ksb[j * 72 + s8] = *(const bf16x8*)&g_qkh[so];
        *(bf16x8*)&ksl[j * 72 + s8] = *(const bf16x8*)&g_qkl[so];
    }
    // --- V transpose: paired keys -> dword writes, 4B lane stride ---
    for (int idx = tid; idx < 512; idx += 256) {
        const int j2 = idx & 63, d8 = (idx >> 6) * 8;
        const size_t sa = mbase + ((size_t)tk[2 * j2] << 6) + d8;
        const size_t sb = mbase + ((size_t)tk[2 * j2 + 1] << 6) + d8;
        const bf16x8 ha = *(const bf16x8*)&g_vh[sa];
        const bf16x8 hb = *(const bf16x8*)&g_vh[sb];
        const bf16x8 la = *(const bf16x8*)&g_vl[sa];
        const bf16x8 lb = *(const bf16x8*)&g_vl[sb];
#pragma unroll
        for (int e = 0; e < 8; e++) {
            const unsigned wh = (unsigned)(unsigned short)ha[e]
                              | ((unsigned)(unsigned short)hb[e] << 16);
            const unsigned wl = (unsigned)(unsigned short)la[e]
                              | ((unsigned)(unsigned short)lb[e] << 16);
            *(unsigned*)&vth[(d8 + e) * 136 + 2 * j2] = wh;
            *(unsigned*)&vtl[(d8 + e) * 136 + 2 * j2] = wl;
        }
    }
    if (tid < 128)
        rnorm[tid] = g_rn[((size_t)m << 12) + tk[tid]];
    __syncthreads();
    const int w = tid >> 6, lane = tid & 63;
    const int llo = lane & 15, lhi = lane >> 4;
    // --- dots: D[q 16 rows of wave][128 keys], K-split 2 x 32 ---
    bf16x8 Ah[2], Al[2];
#pragma unroll
    for (int ks2 = 0; ks2 < 2; ks2++) {
        const int off = (16 * w + llo) * 72 + ks2 * 32 + lhi * 8;
        Ah[ks2] = *(const bf16x8*)&ksb[off];
        Al[ks2] = *(const bf16x8*)&ksl[off];
    }
    f32x4 D[8];
#pragma unroll
    for (int ct = 0; ct < 8; ct++) D[ct] = f32x4{0.f, 0.f, 0.f, 0.f};
#pragma unroll
    for (int ct = 0; ct < 8; ct++) {
#pragma unroll
        for (int ks2 = 0; ks2 < 2; ks2++) {
            const int off = (16 * ct + llo) * 72 + ks2 * 32 + lhi * 8;
            const bf16x8 Bh = *(const bf16x8*)&ksb[off];
            const bf16x8 Bl = *(const bf16x8*)&ksl[off];
            D[ct] = MFMA_BF16(Ah[ks2], Bh, D[ct]);
            D[ct] = MFMA_BF16(Ah[ks2], Bl, D[ct]);
            D[ct] = MFMA_BF16(Al[ks2], Bh, D[ct]);
        }
    }
    // --- epilogue: mask/clamp + row softmax (16-lane reduce) ---
    int myq[4];
#pragma unroll
    for (int r = 0; r < 4; r++) myq[r] = tk[16 * w + lhi * 4 + r];
    float ev[8][4];
    float mx[4] = {-3.4e38f, -3.4e38f, -3.4e38f, -3.4e38f};
#pragma unroll
    for (int ct = 0; ct < 8; ct++) {
        const float rn_ = rnorm[16 * ct + llo] * 0.125f;
        const int tkey = tk[16 * ct + llo];
#pragma unroll
        for (int r = 0; r < 4; r++) {
            float a = D[ct][r];
            a = (myq[r] == tkey) ? -50000.f
                : fminf(fmaxf(a * rn_, -30.f), 30.f);
            ev[ct][r] = a;
            mx[r] = fmaxf(mx[r], a);
        }
    }
    float inv_s[4], lse_[4];
#pragma unroll
    for (int r = 0; r < 4; r++) {
        float mr = mx[r];
        mr = fmaxf(mr, __shfl_xor(mr, 1));
        mr = fmaxf(mr, __shfl_xor(mr, 2));
        mr = fmaxf(mr, __shfl_xor(mr, 4));
        mr = fmaxf(mr, __shfl_xor(mr, 8));
        float s = 0.f;
#pragma unroll
        for (int ct = 0; ct < 8; ct++) {
            const float e = __expf(ev[ct][r] - mr);
            ev[ct][r] = e;
            s += e;
        }
        s += __shfl_xor(s, 1);
        s += __shfl_xor(s, 2);
        s += __shfl_xor(s, 4);
        s += __shfl_xor(s, 8);
        inv_s[r] = 1.0f / s;
        lse_[r] = mr + __logf(s);
    }
    __syncthreads();   // all ksb/ksl dots reads done -> alias as p^T
    short* __restrict__ pth = ksb;   // [64 rows][136 keys]
    short* __restrict__ ptl = ksl;
#pragma unroll
    for (int ct = 0; ct < 8; ct++) {
        const int key = 16 * ct + llo;
#pragma unroll
        for (int r = 0; r < 4; r++) {
            const float ph = ev[ct][r] * inv_s[r];
            const unsigned short hh_ = f2bf(ph);
            const int q = 16 * w + lhi * 4 + r;
            pth[q * 136 + key] = (short)hh_;
            ptl[q * 136 + key] = (short)f2bf(ph - bf2f(hh_));
        }
    }
    if (llo == 0) {
#pragma unroll
        for (int r = 0; r < 4; r++)
            g_logits[((size_t)m * 8 + h) * 4096 + myq[r]] = lse_[r];
    }
    __syncthreads();
    // --- PV: O[q 16 rows][64 dims], K-split 4 x 32 keys ---
    bf16x8 Ph[4], Pl[4];
#pragma unroll
    for (int ks4 = 0; ks4 < 4; ks4++) {
        const int off = (16 * w + llo) * 136 + ks4 * 32 + lhi * 8;
        Ph[ks4] = *(const bf16x8*)&pth[off];
        Pl[ks4] = *(const bf16x8*)&ptl[off];
    }
    float* __restrict__ bo = g_bo + ((((size_t)m * 8 + h) * 4096) << 6);
#pragma unroll
    for (int ct2 = 0; ct2 < 4; ct2++) {
        f32x4 O = f32x4{0.f, 0.f, 0.f, 0.f};
#pragma unroll
        for (int ks4 = 0; ks4 < 4; ks4++) {
            const int off = (16 * ct2 + llo) * 136 + ks4 * 32 + lhi * 8;
            const bf16x8 Vh = *(const bf16x8*)&vth[off];
            const bf16x8 Vl = *(const bf16x8*)&vtl[off];
            O = MFMA_BF16(Ph[ks4], Vh, O);
            O = MFMA_BF16(Ph[ks4], Vl, O);
            O = MFMA_BF16(Pl[ks4], Vh, O);
        }
#pragma unroll
        for (int r = 0; r < 4; r++)
            bo[((size_t)myq[r] << 6) + 16 * ct2 + llo] = O[r];
    }
}

// ---------------------------------------------------------------------------
// Kernel 4: round combination (unchanged).
// ---------------------------------------------------------------------------
__global__ __launch_bounds__(256) void combine()
{
    const int idx = blockIdx.x * 256 + threadIdx.x;
    const int g = idx & 3;                 // 16-dim group
    const int t = (idx >> 2) & 4095;
    const int m = idx >> 14;
    const float* __restrict__ lg = g_logits + (size_t)m * 8 * 4096 + t;
    float l[8], mx = -3.4e38f;
#pragma unroll
    for (int h = 0; h < 8; h++) {
        l[h] = lg[(size_t)h * 4096];
        mx = fmaxf(mx, l[h]);
    }
    float s = 0.f;
#pragma unroll
    for (int h = 0; h < 8; h++) { l[h] = __expf(l[h] - mx); s += l[h]; }
    const float inv = 1.0f / s;
    const float* __restrict__ bo = g_bo
        + (((size_t)m * 8) * 4096 + t) * 64 + g * 16;
    float4 o0 = {0, 0, 0, 0}, o1 = {0, 0, 0, 0}, o2 = {0, 0, 0, 0}, o3 = {0, 0, 0, 0};
#pragma unroll
    for (int h = 0; h < 8; h++) {
        const float w = l[h] * inv;
        const size_t ho = (size_t)h * 4096 * 64;
        const float4 v0 = *(const float4*)&bo[ho + 0];
        const float4 v1 = *(const float4*)&bo[ho + 4];
        const float4 v2 = *(const float4*)&bo[ho + 8];
        const float4 v3 = *(const float4*)&bo[ho + 12];
        o0.x += w * v0.x; o0.y += w * v0.y; o0.z += w * v0.z; o0.w += w * v0.w;
        o1.x += w * v1.x; o1.y += w * v1.y; o1.z += w * v1.z; o1.w += w * v1.w;
        o2.x += w * v2.x; o2.y += w * v2.y; o2.z += w * v2.z; o2.w += w * v2.w;
        o3.x += w * v3.x; o3.y += w * v3.y; o3.z += w * v3.z; o3.w += w * v3.w;
    }
    float* __restrict__ cd = g_ctx
        + ((size_t)(m >> 4) * 4096 + t) * 1024 + (m & 15) * 64 + g * 16;
    *(float4*)&cd[0]  = o0;
    *(float4*)&cd[4]  = o1;
    *(float4*)&cd[8]  = o2;
    *(float4*)&cd[12] = o3;
}

// ---------------------------------------------------------------------------
// Kernel 5: out = ctx @ w_out^T + b_out via bf16 hi/lo 3-term MFMA.
// Same structure as v_gemm. grid (64, 8).
// ---------------------------------------------------------------------------
__global__ __launch_bounds__(256) void out_gemm(
    const float* __restrict__ w_out, const float* __restrict__ b_out,
    float* __restrict__ out)
{
    __shared__ __align__(16) short Ah[128 * 40], Al[128 * 40];
    __shared__ __align__(16) short Bh[128 * 40], Bl[128 * 40];
    const int tid = threadIdx.x;
    const int row0 = blockIdx.x * 128;
    const int col0 = blockIdx.y * 128;
    const int w = tid >> 6, lane = tid & 63;
    const int llo = lane & 15, lhi = lane >> 4;
    const int wr0 = (w >> 1) * 64, wc0 = (w & 1) * 64;
    const int lr = tid >> 1;
    const int lh = (tid & 1) * 16;
    f32x4 Acc[4][4];
#pragma unroll
    for (int rt = 0; rt < 4; rt++)
#pragma unroll
        for (int ct = 0; ct < 4; ct++) Acc[rt][ct] = f32x4{0.f, 0.f, 0.f, 0.f};

    for (int k0 = 0; k0 < 1024; k0 += 32) {
        float av[16], bv[16];
#pragma unroll
        for (int q4 = 0; q4 < 4; q4++) {
            *(float4*)&av[q4 * 4] =
                *(const float4*)(g_ctx + (size_t)(row0 + lr) * 1024 + k0 + lh + q4 * 4);
            *(float4*)&bv[q4 * 4] =
                *(const float4*)(w_out + (size_t)(col0 + lr) * 1024 + k0 + lh + q4 * 4);
        }
        __syncthreads();
        short ah[16], al2[16], bh2[16], bl2[16];
#pragma unroll
        for (int e = 0; e < 16; e++) {
            unsigned short hv = f2bf(av[e]);
            ah[e] = (short)hv;
            al2[e] = (short)f2bf(av[e] - bf2f(hv));
            hv = f2bf(bv[e]);
            bh2[e] = (short)hv;
            bl2[e] = (short)f2bf(bv[e] - bf2f(hv));
        }
        *(bf16x8*)&Ah[lr * 40 + lh] = *(bf16x8*)&ah[0];
        *(bf16x8*)&Ah[lr * 40 + lh + 8] = *(bf16x8*)&ah[8];
        *(bf16x8*)&Al[lr * 40 + lh] = *(bf16x8*)&al2[0];
        *(bf16x8*)&Al[lr * 40 + lh + 8] = *(bf16x8*)&al2[8];
        *(bf16x8*)&Bh[lr * 40 + lh] = *(bf16x8*)&bh2[0];
        *(bf16x8*)&Bh[lr * 40 + lh + 8] = *(bf16x8*)&bh2[8];
        *(bf16x8*)&Bl[lr * 40 + lh] = *(bf16x8*)&bl2[0];
        *(bf16x8*)&Bl[lr * 40 + lh + 8] = *(bf16x8*)&bl2[8];
        __syncthreads();
        bf16x8 Afh[4], Afl[4];
#pragma unroll
        for (int rt = 0; rt < 4; rt++) {
            const int off = (wr0 + rt * 16 + llo) * 40 + lhi * 8;
            Afh[rt] = *(const bf16x8*)&Ah[off];
            Afl[rt] = *(const bf16x8*)&Al[off];
        }
#pragma unroll
        for (int ct = 0; ct < 4; ct++) {
            const int off = (wc0 + ct * 16 + llo) * 40 + lhi * 8;
            const bf16x8 Bfh = *(const bf16x8*)&Bh[off];
            const bf16x8 Bfl = *(const bf16x8*)&Bl[off];
#pragma unroll
            for (int rt = 0; rt < 4; rt++) {
                Acc[rt][ct] = MFMA_BF16(Afh[rt], Bfh, Acc[rt][ct]);
                Acc[rt][ct] = MFMA_BF16(Afh[rt], Bfl, Acc[rt][ct]);
                Acc[rt][ct] = MFMA_BF16(Afl[rt], Bfh, Acc[rt][ct]);
            }
        }
    }
#pragma unroll
    for (int ct = 0; ct < 4; ct++) {
        const int col = col0 + wc0 + ct * 16 + llo;
        const float bias = b_out[col];
#pragma unroll
        for (int rt = 0; rt < 4; rt++) {
#pragma unroll
            for (int r = 0; r < 4; r++) {
                const int row = row0 + wr0 + rt * 16 + lhi * 4 + r;
                out[(size_t)row * 1024 + col] = Acc[rt][ct][r] + bias;
            }
        }
    }
}

// ---------------------------------------------------------------------------
extern "C" void kernel_launch(void* const* d_in, const int* in_sizes, int n_in,
                              void* d_out, int out_size, void* d_ws, size_t ws_size,
                              hipStream_t stream)
{
    (void)in_sizes; (void)n_in; (void)out_size; (void)d_ws; (void)ws_size;
    const float* x     = (const float*)d_in[0];
    const float* w_qk  = (const float*)d_in[1];
    const float* w_v   = (const float*)d_in[2];
    const float* w_out = (const float*)d_in[3];
    const float* b_out = (const float*)d_in[4];
    const float* rot   = (const float*)d_in[5];

    qk_gemm<<<dim3(64, 8), 256, 0, stream>>>(x, w_qk);
    v_gemm<<<dim3(64, 8), 256, 0, stream>>>(x, w_v);
    qk_prep<<<512, 256, 0, stream>>>();
    hash_kernel<<<512, 256, 0, stream>>>(rot);
    sort_kernel<<<256, 256, 0, stream>>>();
    attn_chunk<<<16384, 256, 0, stream>>>();
    combine<<<2048, 256, 0, stream>>>();
    out_gemm<<<dim3(64, 8), 256, 0, stream>>>(w_out, b_out, (float*)d_out);
}